// Round 5
// baseline (229.069 us; speedup 1.0000x reference)
//
#include <hip/hip_runtime.h>

#define EPS_ 1e-6f

typedef __attribute__((ext_vector_type(8))) short bf16x8;
typedef __attribute__((ext_vector_type(4))) float f32x4;

__device__ __forceinline__ unsigned short f2b(float f){
  union { float f; unsigned int u; } v; v.f = f;
  unsigned int r = v.u + 0x7fffu + ((v.u >> 16) & 1u);
  return (unsigned short)(r >> 16);
}

// ---------- K0: weight prep ----------
__global__ __launch_bounds__(256) void k_cvt(
    const float* __restrict__ Wq, const float* __restrict__ Wk,
    const float* __restrict__ Wv, const float* __restrict__ Wo,
    float* __restrict__ fWkT, float* __restrict__ fWvT,
    unsigned short* __restrict__ bWq, unsigned short* __restrict__ bWo){
  int i = blockIdx.x*256 + threadIdx.x;     // 65536
  int o = i >> 8, c = i & 255;
  fWkT[c*256+o] = Wk[i];
  fWvT[c*256+o] = Wv[i];
  bWq[i] = f2b(Wq[i]);
  bWo[i] = f2b(Wo[i]);
}

// ---------- K1: style LN + K/V proj (fp32), bf16 out ----------
// Kb: [bh][n][d] (d-contig)   Vb: [bh][d][n] (n-contig)
__global__ __launch_bounds__(256) void k_kv(
    const float* __restrict__ s, const float* __restrict__ lns_w,
    const float* __restrict__ lns_b,
    const float* __restrict__ fWkT, const float* __restrict__ fWvT,
    unsigned short* __restrict__ Kb, unsigned short* __restrict__ Vb){
  __shared__ float sn[256];
  __shared__ float red[8];
  int t = threadIdx.x;
  int bn = blockIdx.x;                      // b*256 + n
  float v0 = s[(size_t)bn*256 + t];
  float s1 = v0, s2 = v0*v0;
  #pragma unroll
  for (int off=32; off; off>>=1){ s1 += __shfl_down(s1, off); s2 += __shfl_down(s2, off); }
  int lane = t & 63, wv = t >> 6;
  if (lane == 0){ red[wv] = s1; red[4+wv] = s2; }
  __syncthreads();
  float a = red[0]+red[1]+red[2]+red[3];
  float q = red[4]+red[5]+red[6]+red[7];
  float mu = a * (1.f/256.f);
  float rstd = rsqrtf(q*(1.f/256.f) - mu*mu + EPS_);
  sn[t] = (v0 - mu)*rstd*lns_w[t] + lns_b[t];
  __syncthreads();
  float ak0=0.f, ak1=0.f, av0=0.f, av1=0.f;
  for (int c=0; c<256; c+=2){
    float u0 = sn[c], u1 = sn[c+1];
    ak0 += fWkT[c*256+t]*u0;  ak1 += fWkT[(c+1)*256+t]*u1;
    av0 += fWvT[c*256+t]*u0;  av1 += fWvT[(c+1)*256+t]*u1;
  }
  int b = bn >> 8, n = bn & 255, h = t >> 5, d = t & 31;
  Kb[(((size_t)b*8+h)*256 + n)*32 + d] = f2b(ak0+ak1);
  Vb[(((size_t)b*8+h)*32 + d)*256 + n] = f2b(av0+av1);
}

// ---------- K2: LN(x) + Q-proj MFMA. qbuf: [bh][p][d] bf16 ----------
// Single global pass: stage x as bf16 in LDS during stats, normalize in place.
__global__ __launch_bounds__(256) void k_lnq(
    const float* __restrict__ x, const float* __restrict__ ln_w,
    const float* __restrict__ ln_b, const unsigned short* __restrict__ bWq,
    unsigned short* __restrict__ qbuf){
  __shared__ unsigned short hn[64*264];     // [p][256c + 8 pad]
  __shared__ float st[512];
  int t = threadIdx.x;
  int tile = blockIdx.x;
  int b = tile >> 8, p0 = (tile & 255) << 6;
  int pp = t & 63, seg = t >> 6;
  const float* xb = x + ((size_t)b << 22) + p0 + pp;
  // pass 1: read x once, accumulate stats, stage bf16 copy in LDS
  float s1=0.f, s2=0.f;
  for (int k=0;k<32;++k){
    int c = seg*64 + 2*k;
    float v0 = xb[(size_t)c << 14];
    float v1 = xb[(size_t)(c+1) << 14];
    s1 += v0+v1; s2 += v0*v0+v1*v1;
    *(unsigned int*)&hn[pp*264 + c] =
        (unsigned int)f2b(v0) | ((unsigned int)f2b(v1)<<16);
  }
  st[seg*64+pp] = s1; st[256+seg*64+pp] = s2;
  __syncthreads();
  float a = st[pp]+st[64+pp]+st[128+pp]+st[192+pp];
  float q = st[256+pp]+st[320+pp]+st[384+pp]+st[448+pp];
  float mu = a*(1.f/256.f);
  float rstd = rsqrtf(q*(1.f/256.f)-mu*mu+EPS_);
  // pass 2: normalize in place from LDS (thread reads only its own writes)
  for (int k=0;k<32;++k){
    int c = seg*64 + 2*k;
    unsigned int pk = *(unsigned int*)&hn[pp*264 + c];
    float v0 = __uint_as_float(pk << 16);
    float v1 = __uint_as_float(pk & 0xffff0000u);
    v0 = (v0-mu)*rstd*ln_w[c]   + ln_b[c];
    v1 = (v1-mu)*rstd*ln_w[c+1] + ln_b[c+1];
    *(unsigned int*)&hn[pp*264 + c] =
        (unsigned int)f2b(v0) | ((unsigned int)f2b(v1)<<16);
  }
  __syncthreads();
  // MFMA: q[o][p] = sum_c Wq[o][c]*hn[c][p]
  int lane = t & 63, w = t >> 6;
  int quad = lane >> 4, l16 = lane & 15;
  f32x4 acc[4][4];
  #pragma unroll
  for (int ot=0;ot<4;++ot)
    #pragma unroll
    for (int pt=0;pt<4;++pt) acc[ot][pt] = (f32x4){0.f,0.f,0.f,0.f};
  const unsigned short* wq = bWq + (size_t)(w*64 + l16)*256 + quad*8;
  for (int ks=0; ks<8; ++ks){
    bf16x8 bfr[4], afr[4];
    #pragma unroll
    for (int pt=0;pt<4;++pt)
      bfr[pt] = *(const bf16x8*)&hn[(pt*16+l16)*264 + ks*32 + quad*8];
    #pragma unroll
    for (int ot=0;ot<4;++ot)
      afr[ot] = *(const bf16x8*)(wq + ot*16*256 + ks*32);
    #pragma unroll
    for (int ot=0;ot<4;++ot)
      #pragma unroll
      for (int pt=0;pt<4;++pt)
        acc[ot][pt] = __builtin_amdgcn_mfma_f32_16x16x32_bf16(afr[ot], bfr[pt], acc[ot][pt], 0,0,0);
  }
  #pragma unroll
  for (int ot=0;ot<4;++ot){
    int o = w*64 + ot*16 + quad*4;          // 4 consecutive o, within one head
    int h = o >> 5, db = o & 31;
    #pragma unroll
    for (int pt=0;pt<4;++pt){
      int p = p0 + pt*16 + l16;
      unsigned short pk[4];
      #pragma unroll
      for (int r=0;r<4;++r) pk[r] = f2b(acc[ot][pt][r]);
      *(uint2*)&qbuf[(((size_t)b*8+h)*16384 + p)*32 + db] = *(uint2*)pk;
    }
  }
}

// ---------- K3: attention. wave = 16 positions x 1 head ----------
__global__ __launch_bounds__(256) void k_attn(
    const unsigned short* __restrict__ qbuf, const unsigned short* __restrict__ Kb,
    const unsigned short* __restrict__ Vb, unsigned short* __restrict__ abuf){
  __shared__ unsigned short Pt[4*16*264];   // per-wave P transpose [p][n+pad]
  int t = threadIdx.x;
  int bh = blockIdx.y;
  int b = bh >> 3, h = bh & 7;
  int w = t >> 6, lane = t & 63, quad = lane >> 4, l16 = lane & 15;
  int p0 = blockIdx.x*64 + w*16;
  // A-frag: q[m=p][k=d]
  bf16x8 qf = *(const bf16x8*)&qbuf[((size_t)bh*16384 + p0 + l16)*32 + quad*8];
  f32x4 sc[16];
  const unsigned short* kb = Kb + (size_t)bh*8192 + quad*8;
  #pragma unroll
  for (int nt=0;nt<16;++nt){
    bf16x8 kf = *(const bf16x8*)(kb + (size_t)(nt*16+l16)*32);
    f32x4 z = {0.f,0.f,0.f,0.f};
    sc[nt] = __builtin_amdgcn_mfma_f32_16x16x32_bf16(qf, kf, z, 0,0,0);
  }
  // row max (rows p=quad*4+r; 16-lane groups share rows)
  float mx[4] = {-1e30f,-1e30f,-1e30f,-1e30f};
  #pragma unroll
  for (int nt=0;nt<16;++nt)
    #pragma unroll
    for (int r=0;r<4;++r) mx[r] = fmaxf(mx[r], sc[nt][r]);
  #pragma unroll
  for (int m=1;m<16;m<<=1)
    #pragma unroll
    for (int r=0;r<4;++r) mx[r] = fmaxf(mx[r], __shfl_xor(mx[r], m, 64));
  // exp2-folded softmax numerator; sum; defer 1/l past PV
  const float c1 = 0.17677669529663689f * 1.44269504088896341f; // scale*log2e
  float mxc[4], sm[4] = {0.f,0.f,0.f,0.f};
  #pragma unroll
  for (int r=0;r<4;++r) mxc[r] = mx[r]*c1;
  #pragma unroll
  for (int nt=0;nt<16;++nt)
    #pragma unroll
    for (int r=0;r<4;++r){
      float p = exp2f(fmaf(sc[nt][r], c1, -mxc[r]));
      sc[nt][r] = p; sm[r] += p;
    }
  #pragma unroll
  for (int m=1;m<16;m<<=1)
    #pragma unroll
    for (int r=0;r<4;++r) sm[r] += __shfl_xor(sm[r], m, 64);
  // P (D-layout) -> LDS [p][n], truncation pack (P in (0,1])
  unsigned short* Pw = Pt + w*16*264;
  #pragma unroll
  for (int nt=0;nt<16;++nt)
    #pragma unroll
    for (int r=0;r<4;++r)
      Pw[(quad*4+r)*264 + nt*16 + l16] =
          (unsigned short)(__float_as_uint(sc[nt][r]) >> 16);
  // no barrier: Pt region is wave-private; lgkmcnt ordering suffices
  // PV: att[p][d] = sum_n P[p][n] V[n][d]
  f32x4 av[2] = {{0.f,0.f,0.f,0.f},{0.f,0.f,0.f,0.f}};
  const unsigned short* vb = Vb + (size_t)bh*8192 + quad*8;
  for (int ks=0; ks<8; ++ks){
    bf16x8 pf = *(const bf16x8*)&Pw[l16*264 + ks*32 + quad*8];
    #pragma unroll
    for (int dt=0; dt<2; ++dt){
      bf16x8 vf = *(const bf16x8*)(vb + (size_t)(dt*16+l16)*256 + ks*32);
      av[dt] = __builtin_amdgcn_mfma_f32_16x16x32_bf16(pf, vf, av[dt], 0,0,0);
    }
  }
  float inv[4];
  #pragma unroll
  for (int r=0;r<4;++r) inv[r] = 1.f/sm[r];
  // store att -> abuf [b][p][c] bf16 (normalize here: rows match lane quad)
  #pragma unroll
  for (int dt=0; dt<2; ++dt)
    #pragma unroll
    for (int r=0;r<4;++r)
      abuf[((size_t)b*16384 + p0 + quad*4 + r)*256 + h*32 + dt*16 + l16]
          = f2b(av[dt][r]*inv[r]);
}

// ---------- K4: Wo MFMA + bias + residual (32-position tiles) ----------
__global__ __launch_bounds__(256) void k_out(
    const unsigned short* __restrict__ abuf, const unsigned short* __restrict__ bWo,
    const float* __restrict__ bo, const float* __restrict__ x,
    float* __restrict__ out){
  int t = threadIdx.x;
  int tile = blockIdx.x;                    // 0..1023
  int b = tile >> 9, p0 = (tile & 511) << 5;
  int w = t >> 6, lane = t & 63, quad = lane >> 4, l16 = lane & 15;
  f32x4 acc[4][2];
  #pragma unroll
  for (int ot=0;ot<4;++ot)
    #pragma unroll
    for (int pt=0;pt<2;++pt) acc[ot][pt] = (f32x4){0.f,0.f,0.f,0.f};
  const unsigned short* wo = bWo + (size_t)(w*64 + l16)*256 + quad*8;
  const unsigned short* ab = abuf + ((size_t)b*16384 + p0 + l16)*256 + quad*8;
  for (int ks=0; ks<8; ++ks){
    bf16x8 bfr[2], afr[4];
    #pragma unroll
    for (int pt=0;pt<2;++pt)
      bfr[pt] = *(const bf16x8*)(ab + (size_t)pt*16*256 + ks*32);
    #pragma unroll
    for (int ot=0;ot<4;++ot)
      afr[ot] = *(const bf16x8*)(wo + (size_t)ot*16*256 + ks*32);
    #pragma unroll
    for (int ot=0;ot<4;++ot)
      #pragma unroll
      for (int pt=0;pt<2;++pt)
        acc[ot][pt] = __builtin_amdgcn_mfma_f32_16x16x32_bf16(afr[ot], bfr[pt], acc[ot][pt], 0,0,0);
  }
  #pragma unroll
  for (int ot=0;ot<4;++ot){
    int o = w*64 + ot*16 + quad*4;
    #pragma unroll
    for (int pt=0;pt<2;++pt){
      int p = p0 + pt*16 + l16;
      #pragma unroll
      for (int r=0;r<4;++r){
        size_t idx = (((size_t)b*256 + o + r) << 14) + p;
        out[idx] = acc[ot][pt][r] + bo[o+r] + x[idx];
      }
    }
  }
}

extern "C" void kernel_launch(void* const* d_in, const int* in_sizes, int n_in,
                              void* d_out, int out_size, void* d_ws, size_t ws_size,
                              hipStream_t stream) {
  const float* x     = (const float*)d_in[0];
  const float* s     = (const float*)d_in[1];
  const float* ln_w  = (const float*)d_in[2];
  const float* ln_b  = (const float*)d_in[3];
  const float* lns_w = (const float*)d_in[4];
  const float* lns_b = (const float*)d_in[5];
  const float* Wq    = (const float*)d_in[6];
  const float* Wk    = (const float*)d_in[7];
  const float* Wv    = (const float*)d_in[8];
  const float* Wo    = (const float*)d_in[9];
  const float* bo    = (const float*)d_in[10];
  float* out = (float*)d_out;

  unsigned short* abuf = (unsigned short*)d_ws;            // 8388608 us
  float* fWkT = (float*)(abuf + 8388608);                  // 65536 f
  float* fWvT = fWkT + 65536;                              // 65536 f
  unsigned short* bWq = (unsigned short*)(fWvT + 65536);   // 65536 us
  unsigned short* bWo = bWq + 65536;                       // 65536 us
  unsigned short* Kb  = bWo + 65536;                       // 131072 us
  unsigned short* Vb  = Kb + 131072;                       // 131072 us
  // qbuf: first 16.78 MB of d_out (fully overwritten by k_out afterwards)
  unsigned short* qbuf = (unsigned short*)d_out;

  k_cvt <<<256, 256, 0, stream>>>(Wq, Wk, Wv, Wo, fWkT, fWvT, bWq, bWo);
  k_kv  <<<512, 256, 0, stream>>>(s, lns_w, lns_b, fWkT, fWvT, Kb, Vb);
  k_lnq <<<512, 256, 0, stream>>>(x, ln_w, ln_b, bWq, qbuf);
  k_attn<<<dim3(256,16), 256, 0, stream>>>(qbuf, Kb, Vb, abuf);
  k_out <<<1024, 256, 0, stream>>>(abuf, bWo, bo, x, out);
}

// Round 6
// 216.707 us; speedup vs baseline: 1.0570x; 1.0570x over previous
//
#include <hip/hip_runtime.h>

#define EPS_ 1e-6f

typedef __attribute__((ext_vector_type(8))) short bf16x8;
typedef __attribute__((ext_vector_type(4))) short bf16x4;
typedef __attribute__((ext_vector_type(4))) float f32x4;

__device__ __forceinline__ unsigned short f2b(float f){
  union { float f; unsigned int u; } v; v.f = f;
  unsigned int r = v.u + 0x7fffu + ((v.u >> 16) & 1u);
  return (unsigned short)(r >> 16);
}

// ---------- K0: weight prep ----------
__global__ __launch_bounds__(256) void k_cvt(
    const float* __restrict__ Wq, const float* __restrict__ Wk,
    const float* __restrict__ Wv, const float* __restrict__ Wo,
    float* __restrict__ fWkT, float* __restrict__ fWvT,
    unsigned short* __restrict__ bWq, unsigned short* __restrict__ bWo){
  int i = blockIdx.x*256 + threadIdx.x;     // 65536
  int o = i >> 8, c = i & 255;
  fWkT[c*256+o] = Wk[i];
  fWvT[c*256+o] = Wv[i];
  bWq[i] = f2b(Wq[i]);
  bWo[i] = f2b(Wo[i]);
}

// ---------- K1: style LN + K/V proj (fp32), bf16 out ----------
// Kb: [bh][n][d] (d-contig)   Vb: [bh][d][n] (n-contig)
__global__ __launch_bounds__(256) void k_kv(
    const float* __restrict__ s, const float* __restrict__ lns_w,
    const float* __restrict__ lns_b,
    const float* __restrict__ fWkT, const float* __restrict__ fWvT,
    unsigned short* __restrict__ Kb, unsigned short* __restrict__ Vb){
  __shared__ float sn[256];
  __shared__ float red[8];
  int t = threadIdx.x;
  int bn = blockIdx.x;                      // b*256 + n
  float v0 = s[(size_t)bn*256 + t];
  float s1 = v0, s2 = v0*v0;
  #pragma unroll
  for (int off=32; off; off>>=1){ s1 += __shfl_down(s1, off); s2 += __shfl_down(s2, off); }
  int lane = t & 63, wv = t >> 6;
  if (lane == 0){ red[wv] = s1; red[4+wv] = s2; }
  __syncthreads();
  float a = red[0]+red[1]+red[2]+red[3];
  float q = red[4]+red[5]+red[6]+red[7];
  float mu = a * (1.f/256.f);
  float rstd = rsqrtf(q*(1.f/256.f) - mu*mu + EPS_);
  sn[t] = (v0 - mu)*rstd*lns_w[t] + lns_b[t];
  __syncthreads();
  float ak0=0.f, ak1=0.f, av0=0.f, av1=0.f;
  for (int c=0; c<256; c+=2){
    float u0 = sn[c], u1 = sn[c+1];
    ak0 += fWkT[c*256+t]*u0;  ak1 += fWkT[(c+1)*256+t]*u1;
    av0 += fWvT[c*256+t]*u0;  av1 += fWvT[(c+1)*256+t]*u1;
  }
  int b = bn >> 8, n = bn & 255, h = t >> 5, d = t & 31;
  Kb[(((size_t)b*8+h)*256 + n)*32 + d] = f2b(ak0+ak1);
  Vb[(((size_t)b*8+h)*32 + d)*256 + n] = f2b(av0+av1);
}

// ---------- K2: fused LN + Qproj + attention + Wo + residual ----------
// 512 blocks (= 2/CU), 64 positions each. 4 waves.
__global__ __launch_bounds__(256,2) void k_mega(
    const float* __restrict__ x, const float* __restrict__ ln_w,
    const float* __restrict__ ln_b,
    const unsigned short* __restrict__ bWq, const unsigned short* __restrict__ bWo,
    const unsigned short* __restrict__ Kb, const unsigned short* __restrict__ Vb,
    const float* __restrict__ bo, float* __restrict__ out){
  __shared__ unsigned short buf1[64*264];   // [p][c]: hn, then [p][o]: q  (33792 B)
  __shared__ unsigned short Pt[4*16*264];   // per-wave P [p][n]          (33792 B)
  __shared__ unsigned short atth[2][64*40]; // per-head att [p][d] dbuf   (10240 B)
  __shared__ float st[512];                 //                            ( 2048 B)
  int t = threadIdx.x;
  int tile = blockIdx.x;                    // 0..511
  int b = tile >> 8, p0 = (tile & 255) << 6;
  int pp = t & 63, seg = t >> 6;
  const float* xb = x + ((size_t)b << 22) + p0 + pp;

  // ---- LN: single global pass, stage bf16 in buf1, stats, normalize ----
  float s1=0.f, s2=0.f;
  for (int k=0;k<32;++k){
    int c = seg*64 + 2*k;
    float v0 = xb[(size_t)c << 14];
    float v1 = xb[(size_t)(c+1) << 14];
    s1 += v0+v1; s2 += v0*v0+v1*v1;
    *(unsigned int*)&buf1[pp*264 + c] =
        (unsigned int)f2b(v0) | ((unsigned int)f2b(v1)<<16);
  }
  st[seg*64+pp] = s1; st[256+seg*64+pp] = s2;
  __syncthreads();
  float a = st[pp]+st[64+pp]+st[128+pp]+st[192+pp];
  float q = st[256+pp]+st[320+pp]+st[384+pp]+st[448+pp];
  float mu = a*(1.f/256.f);
  float rstd = rsqrtf(q*(1.f/256.f)-mu*mu+EPS_);
  for (int k=0;k<32;++k){
    int c = seg*64 + 2*k;
    unsigned int pk = *(unsigned int*)&buf1[pp*264 + c];
    float v0 = __uint_as_float(pk << 16);
    float v1 = __uint_as_float(pk & 0xffff0000u);
    v0 = (v0-mu)*rstd*ln_w[c]   + ln_b[c];
    v1 = (v1-mu)*rstd*ln_w[c+1] + ln_b[c+1];
    *(unsigned int*)&buf1[pp*264 + c] =
        (unsigned int)f2b(v0) | ((unsigned int)f2b(v1)<<16);
  }
  __syncthreads();

  // ---- Q-proj MFMA: q[o][p] = sum_c Wq[o][c]*hn[c][p] ----
  int lane = t & 63, w = t >> 6;
  int quad = lane >> 4, l16 = lane & 15;
  {
    f32x4 acc[4][4];
    #pragma unroll
    for (int ot=0;ot<4;++ot)
      #pragma unroll
      for (int pt=0;pt<4;++pt) acc[ot][pt] = (f32x4){0.f,0.f,0.f,0.f};
    const unsigned short* wq = bWq + (size_t)(w*64 + l16)*256 + quad*8;
    for (int ks=0; ks<8; ++ks){
      bf16x8 bfr[4], afr[4];
      #pragma unroll
      for (int pt=0;pt<4;++pt)
        bfr[pt] = *(const bf16x8*)&buf1[(pt*16+l16)*264 + ks*32 + quad*8];
      #pragma unroll
      for (int ot=0;ot<4;++ot)
        afr[ot] = *(const bf16x8*)(wq + ot*16*256 + ks*32);
      #pragma unroll
      for (int ot=0;ot<4;++ot)
        #pragma unroll
        for (int pt=0;pt<4;++pt)
          acc[ot][pt] = __builtin_amdgcn_mfma_f32_16x16x32_bf16(afr[ot], bfr[pt], acc[ot][pt], 0,0,0);
    }
    __syncthreads();                        // all hn reads complete
    // q -> buf1 [p][o], D rows o=quad*4+r contiguous: one b64 per tile
    #pragma unroll
    for (int ot=0;ot<4;++ot){
      int o = w*64 + ot*16 + quad*4;
      #pragma unroll
      for (int pt=0;pt<4;++pt){
        unsigned short pk[4];
        #pragma unroll
        for (int r=0;r<4;++r) pk[r] = f2b(acc[ot][pt][r]);
        *(uint2*)&buf1[(pt*16+l16)*264 + o] = *(uint2*)pk;
      }
    }
  }
  __syncthreads();                          // q ready

  // ---- heads loop: attention + Wo accumulation ----
  f32x4 oacc[4][4];
  #pragma unroll
  for (int ot=0;ot<4;++ot)
    #pragma unroll
    for (int pt=0;pt<4;++pt) oacc[ot][pt] = (f32x4){0.f,0.f,0.f,0.f};
  const float c1 = 0.17677669529663689f * 1.44269504088896341f; // scale*log2e
  unsigned short* Pw = Pt + w*16*264;
  for (int h=0; h<8; ++h){
    // QK^T: A = q[m=p][k=d] from LDS, B = K[n][d] from global (L2)
    bf16x8 qf = *(const bf16x8*)&buf1[(w*16+l16)*264 + h*32 + quad*8];
    const unsigned short* kb = Kb + ((size_t)(b*8+h))*8192 + quad*8;
    f32x4 sc[16];
    #pragma unroll
    for (int nt=0;nt<16;++nt){
      bf16x8 kf = *(const bf16x8*)(kb + (size_t)(nt*16+l16)*32);
      f32x4 z = {0.f,0.f,0.f,0.f};
      sc[nt] = __builtin_amdgcn_mfma_f32_16x16x32_bf16(qf, kf, z, 0,0,0);
    }
    // softmax over n (rows p=quad*4+r; 16-lane groups share rows)
    float mx[4] = {-1e30f,-1e30f,-1e30f,-1e30f};
    #pragma unroll
    for (int nt=0;nt<16;++nt)
      #pragma unroll
      for (int r=0;r<4;++r) mx[r] = fmaxf(mx[r], sc[nt][r]);
    #pragma unroll
    for (int m=1;m<16;m<<=1)
      #pragma unroll
      for (int r=0;r<4;++r) mx[r] = fmaxf(mx[r], __shfl_xor(mx[r], m, 64));
    float sm[4] = {0.f,0.f,0.f,0.f};
    #pragma unroll
    for (int r=0;r<4;++r) mx[r] *= c1;
    #pragma unroll
    for (int nt=0;nt<16;++nt)
      #pragma unroll
      for (int r=0;r<4;++r){
        float p = exp2f(fmaf(sc[nt][r], c1, -mx[r]));
        sc[nt][r] = p; sm[r] += p;
      }
    #pragma unroll
    for (int m=1;m<16;m<<=1)
      #pragma unroll
      for (int r=0;r<4;++r) sm[r] += __shfl_xor(sm[r], m, 64);
    float inv[4];
    #pragma unroll
    for (int r=0;r<4;++r) inv[r] = 1.f/sm[r];
    // normalized P -> per-wave LDS [p][n]
    #pragma unroll
    for (int nt=0;nt<16;++nt)
      #pragma unroll
      for (int r=0;r<4;++r)
        Pw[(quad*4+r)*264 + nt*16 + l16] = f2b(sc[nt][r]*inv[r]);
    // PV: att[p][d] = sum_n P[p][n] V[n][d]
    f32x4 av[2] = {{0.f,0.f,0.f,0.f},{0.f,0.f,0.f,0.f}};
    const unsigned short* vb = Vb + ((size_t)(b*8+h))*8192 + quad*8;
    for (int ks=0; ks<8; ++ks){
      bf16x8 pf = *(const bf16x8*)&Pw[l16*264 + ks*32 + quad*8];
      #pragma unroll
      for (int dt=0; dt<2; ++dt){
        bf16x8 vf = *(const bf16x8*)(vb + (size_t)(dt*16+l16)*256 + ks*32);
        av[dt] = __builtin_amdgcn_mfma_f32_16x16x32_bf16(pf, vf, av[dt], 0,0,0);
      }
    }
    // av (D: row p=quad*4+r, col d=dt*16+l16) -> atth[h&1][p][d]
    unsigned short* ah = atth[h & 1];
    #pragma unroll
    for (int dt=0; dt<2; ++dt)
      #pragma unroll
      for (int r=0;r<4;++r)
        ah[(w*16 + quad*4 + r)*40 + dt*16 + l16] = f2b(av[dt][r]);
    __syncthreads();                        // atth complete for head h
    // Wo partial: A = Wo[o][c=h*32+k], B = atth[n=p][k=d], K=32 (one step)
    const unsigned short* wo = bWo + (size_t)(w*64 + l16)*256 + h*32 + quad*8;
    bf16x8 wfr[4];
    #pragma unroll
    for (int ot=0;ot<4;++ot)
      wfr[ot] = *(const bf16x8*)(wo + (size_t)ot*16*256);
    #pragma unroll
    for (int pt=0;pt<4;++pt){
      bf16x4 blo = *(const bf16x4*)&ah[(pt*16+l16)*40 + quad*8];
      bf16x4 bhi = *(const bf16x4*)&ah[(pt*16+l16)*40 + quad*8 + 4];
      bf16x8 bfr;
      #pragma unroll
      for (int j=0;j<4;++j){ bfr[j] = blo[j]; bfr[4+j] = bhi[j]; }
      #pragma unroll
      for (int ot=0;ot<4;++ot)
        oacc[ot][pt] = __builtin_amdgcn_mfma_f32_16x16x32_bf16(wfr[ot], bfr, oacc[ot][pt], 0,0,0);
    }
  }

  // ---- epilogue: + bias + residual, fp32 store ----
  #pragma unroll
  for (int ot=0;ot<4;++ot){
    int o = w*64 + ot*16 + quad*4;
    #pragma unroll
    for (int pt=0;pt<4;++pt){
      int p = p0 + pt*16 + l16;
      #pragma unroll
      for (int r=0;r<4;++r){
        size_t idx = (((size_t)b*256 + o + r) << 14) + p;
        out[idx] = oacc[ot][pt][r] + bo[o+r] + x[idx];
      }
    }
  }
}

extern "C" void kernel_launch(void* const* d_in, const int* in_sizes, int n_in,
                              void* d_out, int out_size, void* d_ws, size_t ws_size,
                              hipStream_t stream) {
  const float* x     = (const float*)d_in[0];
  const float* s     = (const float*)d_in[1];
  const float* ln_w  = (const float*)d_in[2];
  const float* ln_b  = (const float*)d_in[3];
  const float* lns_w = (const float*)d_in[4];
  const float* lns_b = (const float*)d_in[5];
  const float* Wq    = (const float*)d_in[6];
  const float* Wk    = (const float*)d_in[7];
  const float* Wv    = (const float*)d_in[8];
  const float* Wo    = (const float*)d_in[9];
  const float* bo    = (const float*)d_in[10];
  float* out = (float*)d_out;

  float* fWkT = (float*)d_ws;                              // 65536 f
  float* fWvT = fWkT + 65536;                              // 65536 f
  unsigned short* bWq = (unsigned short*)(fWvT + 65536);   // 65536 us
  unsigned short* bWo = bWq + 65536;                       // 65536 us
  unsigned short* Kb  = bWo + 65536;                       // 131072 us
  unsigned short* Vb  = Kb + 131072;                       // 131072 us
  // total ws: ~1.3 MB

  k_cvt <<<256, 256, 0, stream>>>(Wq, Wk, Wv, Wo, fWkT, fWvT, bWq, bWo);
  k_kv  <<<512, 256, 0, stream>>>(s, lns_w, lns_b, fWkT, fWvT, Kb, Vb);
  k_mega<<<512, 256, 0, stream>>>(x, ln_w, ln_b, bWq, bWo, Kb, Vb, bo, out);
}